// Round 2
// baseline (110.301 us; speedup 1.0000x reference)
//
#include <hip/hip_runtime.h>
#include <hip/hip_bf16.h>

// InfoNCE fused: loss = (1/N) sum_i [ log(sum_j exp(sim_ij)) - sim_ii ]
// sim = (z1/||z1||)@(z2/||z2||)^T / tau.  logits=[pos, diag-masked row] with
// pos == sim_ii => lse over the FULL row (diagonal included).
//
// z1f = bf16(z1n * log2(e)/tau) so exp(sim) = exp2(MFMA output); values in
// [-29,29] in log2 domain -> raw v_exp_f32 (__builtin_amdgcn_exp2f), NOT libm.
//
// R9 vs R8 (47.5 us main): counters showed NO pipe saturated (MfmaUtil 28%
// = exactly the 13.8us of MFMA work, VALUBusy 47% vs ~17us demand) and
// OccupancyPercent 42% ~= 3.3 waves/SIMD: the (256,4) NSETS=4 config
// allocated ~160 unified regs/wave (40 arch VGPR + AGPR block) -> latency-
// bound. Fix: halve per-wave footprint (NSETS 4->2, ~54 regs) under
// __launch_bounds__(256,8) -> 8 waves/SIMD, explicit B double-buffer.
// Predict: occupancy ~2x, main ~27-30us.

typedef __bf16  bf16x8 __attribute__((ext_vector_type(8)));
typedef __bf16  bf16x4 __attribute__((ext_vector_type(4)));
typedef float   f32x4  __attribute__((ext_vector_type(4)));

#if __has_builtin(__builtin_amdgcn_exp2f)
#define EXP2F(x) __builtin_amdgcn_exp2f(x)   // raw v_exp_f32
#else
#define EXP2F(x) exp2f(x)
#endif
#if __has_builtin(__builtin_amdgcn_logf)
#define LOG2F(x) __builtin_amdgcn_logf(x)    // raw v_log_f32
#else
#define LOG2F(x) log2f(x)
#endif

#define DDIM   64
#define TILEB  2048         // bytes per fragment-ordered 16-col tile
#define NSETS  2            // 16-row MFMA sets per wave (32 rows/wave)
#define NW     4            // waves per block
#define BM     (NW * NSETS * 16)   // 128 rows per block
#define CS     32           // column splits -> grid (128,32) = 4096 blocks

// ---------------------------------------------------------------- normalize
// One block per 16-row tile. Thread (r = tid>>4, c = tid&15) loads
// z[row, 4c..4c+4), reduces ||row|| over its 16-lane group, writes the 4
// bf16 values into fragment order:
//   byte off(tile) = (c>>3)*1024 + ((c>>1)&3)*256 + r*16 + (c&1)*8
// Same thread holds row i of both views -> posv[i] = dot(z1f_i, z2f_i)
// computed here (bf16-rounded, matches MFMA diagonal). Zeroes rowsum; block 0
// zeroes d_out (stream-ordered before finalize's atomics).
__global__ __launch_bounds__(256) void norm_frag_kernel(
    const float* __restrict__ z1, const float* __restrict__ z2,
    __hip_bfloat16* __restrict__ z1f, __hip_bfloat16* __restrict__ z2f,
    float* __restrict__ rowsum, float* __restrict__ posv,
    float* __restrict__ out, float scale1, int N)
{
    const int tid  = threadIdx.x;
    const int r    = tid >> 4, c = tid & 15;
    const int tile = blockIdx.x;
    const size_t row = (size_t)tile * 16 + r;
    const size_t off = (size_t)tile * TILEB
                     + ((c >> 3) << 10) + (((c >> 1) & 3) << 8)
                     + (r << 4) + ((c & 1) << 3);

    bf16x4 o1, o2;
    // z1 (scaled by log2(e)/tau)
    {
        float4 v = *(const float4*)(z1 + row * DDIM + c * 4);
        float ss = v.x*v.x + v.y*v.y + v.z*v.z + v.w*v.w;
        #pragma unroll
        for (int o = 8; o; o >>= 1) ss += __shfl_xor(ss, o);
        float inv = scale1 / fmaxf(sqrtf(ss), 1e-12f);
        o1 = (bf16x4){ __float2bfloat16(v.x*inv), __float2bfloat16(v.y*inv),
                       __float2bfloat16(v.z*inv), __float2bfloat16(v.w*inv) };
        *(bf16x4*)((char*)z1f + off) = o1;
    }
    // z2 (unit scale)
    {
        float4 v = *(const float4*)(z2 + row * DDIM + c * 4);
        float ss = v.x*v.x + v.y*v.y + v.z*v.z + v.w*v.w;
        #pragma unroll
        for (int o = 8; o; o >>= 1) ss += __shfl_xor(ss, o);
        float inv = 1.0f / fmaxf(sqrtf(ss), 1e-12f);
        o2 = (bf16x4){ __float2bfloat16(v.x*inv), __float2bfloat16(v.y*inv),
                       __float2bfloat16(v.z*inv), __float2bfloat16(v.w*inv) };
        *(bf16x4*)((char*)z2f + off) = o2;
    }

    // posv[row] = dot of the bf16-rounded rows (log2-domain positive logit)
    float p = (float)o1[0]*(float)o2[0] + (float)o1[1]*(float)o2[1]
            + (float)o1[2]*(float)o2[2] + (float)o1[3]*(float)o2[3];
    #pragma unroll
    for (int o = 8; o; o >>= 1) p += __shfl_xor(p, o);
    if (c == 0) posv[row] = p;

    if (tid < 16) rowsum[(size_t)tile * 16 + tid] = 0.f;
    if (tile == 0 && tid == 0) *out = 0.f;
}

// ---------------------------------------------------------------- main
// 8 waves/SIMD resident (<=64 unified regs/wave). Each wave: 32 rows
// (2 MFMA sets), colspan=512 cols, explicit next-tile B prefetch.
__global__ __launch_bounds__(256, 8) void infonce_main_kernel(
    const __hip_bfloat16* __restrict__ z1f,
    const __hip_bfloat16* __restrict__ z2f,
    float* __restrict__ rowsum,    // fp32, atomic partial rowsums of 2^C
    int N)
{
    const int tid  = threadIdx.x;
    const int wave = tid >> 6;
    const int lane = tid & 63;
    const int q    = lane >> 4;
    const int l15  = lane & 15;

    const int colspan = N / CS;
    const int ntiles  = colspan >> 4;
    const int c0      = blockIdx.y * colspan;
    const int wr      = blockIdx.x * BM + wave * (NSETS * 16);

    // A fragments for NSETS row-tiles (coalesced: fragment-ordered global)
    bf16x8 a0[NSETS], a1[NSETS];
    #pragma unroll
    for (int s = 0; s < NSETS; ++s) {
        const char* ab = (const char*)z1f + (size_t)((wr >> 4) + s) * TILEB + lane * 16;
        a0[s] = *(const bf16x8*)(ab);
        a1[s] = *(const bf16x8*)(ab + 1024);
    }

    float sum[NSETS * 4];
    #pragma unroll
    for (int k = 0; k < NSETS * 4; ++k) sum[k] = 0.f;

    const char* bptr = (const char*)z2f + (size_t)(c0 >> 4) * TILEB + lane * 16;
    const f32x4 kzero = {0.f, 0.f, 0.f, 0.f};

    // prologue: first B tile in flight
    bf16x8 b0 = *(const bf16x8*)(bptr);
    bf16x8 b1 = *(const bf16x8*)(bptr + 1024);
    bptr += TILEB;

    #pragma unroll 2
    for (int t = 0; t < ntiles - 1; ++t) {
        bf16x8 n0 = *(const bf16x8*)(bptr);
        bf16x8 n1 = *(const bf16x8*)(bptr + 1024);
        bptr += TILEB;
        #pragma unroll
        for (int s = 0; s < NSETS; ++s) {
            f32x4 acc = __builtin_amdgcn_mfma_f32_16x16x32_bf16(a0[s], b0, kzero, 0, 0, 0);
            acc = __builtin_amdgcn_mfma_f32_16x16x32_bf16(a1[s], b1, acc, 0, 0, 0);
            sum[s * 4 + 0] += EXP2F(acc[0]);
            sum[s * 4 + 1] += EXP2F(acc[1]);
            sum[s * 4 + 2] += EXP2F(acc[2]);
            sum[s * 4 + 3] += EXP2F(acc[3]);
        }
        b0 = n0; b1 = n1;
    }
    // epilogue: last tile
    #pragma unroll
    for (int s = 0; s < NSETS; ++s) {
        f32x4 acc = __builtin_amdgcn_mfma_f32_16x16x32_bf16(a0[s], b0, kzero, 0, 0, 0);
        acc = __builtin_amdgcn_mfma_f32_16x16x32_bf16(a1[s], b1, acc, 0, 0, 0);
        sum[s * 4 + 0] += EXP2F(acc[0]);
        sum[s * 4 + 1] += EXP2F(acc[1]);
        sum[s * 4 + 2] += EXP2F(acc[2]);
        sum[s * 4 + 3] += EXP2F(acc[3]);
    }

    // reduce each row-sum across the 16 lanes of the quad, then atomics
    #pragma unroll
    for (int k = 0; k < NSETS * 4; ++k) {
        float v = sum[k];
        #pragma unroll
        for (int o = 1; o < 16; o <<= 1) v += __shfl_xor(v, o);
        sum[k] = v;
    }
    if (l15 == 0) {
        #pragma unroll
        for (int s = 0; s < NSETS; ++s)
            #pragma unroll
            for (int i = 0; i < 4; ++i)
                atomicAdd(&rowsum[wr + s * 16 + q * 4 + i], sum[s * 4 + i]);
    }
}

// ---------------------------------------------------------------- finalize
// 64 blocks x 256 threads: thread t handles one row.
__global__ __launch_bounds__(256) void finalize_kernel(
    const float* __restrict__ rowsum, const float* __restrict__ posv,
    float* __restrict__ out, int N)
{
    int row = blockIdx.x * 256 + threadIdx.x;
    float acc = (LOG2F(rowsum[row]) - posv[row]) * (0.69314718055994531f / (float)N);
    #pragma unroll
    for (int o = 32; o; o >>= 1) acc += __shfl_xor(acc, o);
    if ((threadIdx.x & 63) == 0) atomicAdd(out, acc);
}

// ---------------------------------------------------------------- launch
extern "C" void kernel_launch(void* const* d_in, const int* in_sizes, int n_in,
                              void* d_out, int out_size, void* d_ws, size_t ws_size,
                              hipStream_t stream)
{
    const float* z1 = (const float*)d_in[0];
    const float* z2 = (const float*)d_in[1];
    const int N = in_sizes[0] / DDIM;   // 16384

    char* ws = (char*)d_ws;
    __hip_bfloat16* z1f = (__hip_bfloat16*)ws;                  // N*128 B (2 MB)
    __hip_bfloat16* z2f = z1f + (size_t)N * DDIM;               // N*128 B (2 MB)
    float* rowsum = (float*)(ws + 2 * (size_t)N * DDIM * 2);    // N*4 B
    float* posv   = rowsum + N;                                 // N*4 B

    const float kScale = 28.853900817779268f;   // log2(e) / 0.05

    norm_frag_kernel<<<N / 16, 256, 0, stream>>>(z1, z2, z1f, z2f, rowsum,
                                                 posv, (float*)d_out, kScale, N);

    dim3 grid(N / BM, CS);
    infonce_main_kernel<<<grid, NW * 64, 0, stream>>>(z1f, z2f, rowsum, N);

    finalize_kernel<<<N / 256, 256, 0, stream>>>(rowsum, posv, (float*)d_out, N);
}

// Round 3
// 108.153 us; speedup vs baseline: 1.0199x; 1.0199x over previous
//
#include <hip/hip_runtime.h>
#include <hip/hip_bf16.h>

// InfoNCE fused: loss = (1/N) sum_i [ log(sum_j exp(sim_ij)) - sim_ii ]
// sim = (z1/||z1||)@(z2/||z2||)^T / tau.  logits=[pos, diag-masked row] with
// pos == sim_ii => lse over the FULL row (diagonal included).
//
// z1f = bf16(z1n * log2(e)/tau) so exp(sim) = exp2(MFMA output); values in
// [-29,29] in log2 domain -> raw v_exp_f32 (__builtin_amdgcn_exp2f), NOT libm.
//
// R10 vs R9 (51.2 us main): occupancy 42->60% gave NO speedup; B-stream
// traffic doubled (NSETS 2) and time went UP -> bound by redundant per-wave
// B reads from L2 (~21 TB/s of the 34.5 ceiling + ~200cyc latency the 1-tile
// reg prefetch can't cover). Fix: LDS-stage B per BLOCK (global_load_lds,
// 16B), 4-tile/8KB phases, double-buffered, 1 barrier/phase; NSETS back to
// 4 under (256,4). B L2 traffic /8, ds_read latency ~50cyc. Predict main
// ~28-32us, VALUBusy ~72%, MfmaUtil ~45%.

typedef __bf16  bf16x8 __attribute__((ext_vector_type(8)));
typedef __bf16  bf16x4 __attribute__((ext_vector_type(4)));
typedef float   f32x4  __attribute__((ext_vector_type(4)));

#if __has_builtin(__builtin_amdgcn_exp2f)
#define EXP2F(x) __builtin_amdgcn_exp2f(x)   // raw v_exp_f32
#else
#define EXP2F(x) exp2f(x)
#endif
#if __has_builtin(__builtin_amdgcn_logf)
#define LOG2F(x) __builtin_amdgcn_logf(x)    // raw v_log_f32
#else
#define LOG2F(x) log2f(x)
#endif

#define DDIM   64
#define TILEB  2048         // bytes per fragment-ordered 16-col tile
#define NSETS  4            // 16-row MFMA sets per wave (64 rows/wave)
#define NW     4            // waves per block
#define BM     (NW * NSETS * 16)   // 256 rows per block
#define CS     32           // column splits -> grid (64,32) = 2048 blocks
#define PHT    4            // B tiles staged per phase
#define PHB    (PHT * TILEB)       // 8192 B per phase buffer

// global -> LDS async copy, 16 B per lane; LDS dest is wave-uniform base
// + lane*16 (linear layout both sides -- no swizzle, rule #21).
#define GLOAD_LDS(g, l)                                                      \
    __builtin_amdgcn_global_load_lds(                                        \
        (const __attribute__((address_space(1))) void*)(g),                  \
        (__attribute__((address_space(3))) void*)(l), 16, 0, 0)

// ---------------------------------------------------------------- normalize
// One block per 16-row tile. Thread (r = tid>>4, c = tid&15) loads
// z[row, 4c..4c+4), reduces ||row|| over its 16-lane group, writes the 4
// bf16 values into fragment order:
//   byte off(tile) = (c>>3)*1024 + ((c>>1)&3)*256 + r*16 + (c&1)*8
// Same thread holds row i of both views -> posv[i] = dot(z1f_i, z2f_i)
// computed here (bf16-rounded, matches MFMA diagonal). Zeroes rowsum; block 0
// zeroes d_out (stream-ordered before finalize's atomics).
__global__ __launch_bounds__(256) void norm_frag_kernel(
    const float* __restrict__ z1, const float* __restrict__ z2,
    __hip_bfloat16* __restrict__ z1f, __hip_bfloat16* __restrict__ z2f,
    float* __restrict__ rowsum, float* __restrict__ posv,
    float* __restrict__ out, float scale1, int N)
{
    const int tid  = threadIdx.x;
    const int r    = tid >> 4, c = tid & 15;
    const int tile = blockIdx.x;
    const size_t row = (size_t)tile * 16 + r;
    const size_t off = (size_t)tile * TILEB
                     + ((c >> 3) << 10) + (((c >> 1) & 3) << 8)
                     + (r << 4) + ((c & 1) << 3);

    bf16x4 o1, o2;
    // z1 (scaled by log2(e)/tau)
    {
        float4 v = *(const float4*)(z1 + row * DDIM + c * 4);
        float ss = v.x*v.x + v.y*v.y + v.z*v.z + v.w*v.w;
        #pragma unroll
        for (int o = 8; o; o >>= 1) ss += __shfl_xor(ss, o);
        float inv = scale1 / fmaxf(sqrtf(ss), 1e-12f);
        o1 = (bf16x4){ __float2bfloat16(v.x*inv), __float2bfloat16(v.y*inv),
                       __float2bfloat16(v.z*inv), __float2bfloat16(v.w*inv) };
        *(bf16x4*)((char*)z1f + off) = o1;
    }
    // z2 (unit scale)
    {
        float4 v = *(const float4*)(z2 + row * DDIM + c * 4);
        float ss = v.x*v.x + v.y*v.y + v.z*v.z + v.w*v.w;
        #pragma unroll
        for (int o = 8; o; o >>= 1) ss += __shfl_xor(ss, o);
        float inv = 1.0f / fmaxf(sqrtf(ss), 1e-12f);
        o2 = (bf16x4){ __float2bfloat16(v.x*inv), __float2bfloat16(v.y*inv),
                       __float2bfloat16(v.z*inv), __float2bfloat16(v.w*inv) };
        *(bf16x4*)((char*)z2f + off) = o2;
    }

    // posv[row] = dot of the bf16-rounded rows (log2-domain positive logit)
    float p = (float)o1[0]*(float)o2[0] + (float)o1[1]*(float)o2[1]
            + (float)o1[2]*(float)o2[2] + (float)o1[3]*(float)o2[3];
    #pragma unroll
    for (int o = 8; o; o >>= 1) p += __shfl_xor(p, o);
    if (c == 0) posv[row] = p;

    if (tid < 16) rowsum[(size_t)tile * 16 + tid] = 0.f;
    if (tile == 0 && tid == 0) *out = 0.f;
}

// ---------------------------------------------------------------- main
// Per block: 256 rows (4 waves x 4 sets), colspan = N/CS cols. B tiles are
// staged once per block into LDS (each wave stages one 2KB tile per phase,
// 2 x global_load_lds of 1KB), double-buffered; all 4 waves consume the
// same copy via ds_read_b128. One barrier per 4-tile phase.
__global__ __launch_bounds__(256, 4) void infonce_main_kernel(
    const __hip_bfloat16* __restrict__ z1f,
    const __hip_bfloat16* __restrict__ z2f,
    float* __restrict__ rowsum,    // fp32, atomic partial rowsums of 2^C
    int N)
{
    __shared__ __align__(16) char ldsb[2 * PHB];   // 16 KB

    const int tid  = threadIdx.x;
    const int wave = tid >> 6;
    const int lane = tid & 63;
    const int q    = lane >> 4;
    const int l15  = lane & 15;

    const int colspan = N / CS;
    const int ntiles  = colspan >> 4;
    const int nph     = ntiles / PHT;          // 8 phases
    const int c0      = blockIdx.y * colspan;
    const int wr      = blockIdx.x * BM + wave * (NSETS * 16);

    // A fragments for NSETS row-tiles (coalesced: fragment-ordered global)
    bf16x8 a0[NSETS], a1[NSETS];
    #pragma unroll
    for (int s = 0; s < NSETS; ++s) {
        const char* ab = (const char*)z1f + (size_t)((wr >> 4) + s) * TILEB + lane * 16;
        a0[s] = *(const bf16x8*)(ab);
        a1[s] = *(const bf16x8*)(ab + 1024);
    }

    float sum[NSETS * 4];
    #pragma unroll
    for (int k = 0; k < NSETS * 4; ++k) sum[k] = 0.f;

    const char* gB = (const char*)z2f + (size_t)(c0 >> 4) * TILEB;
    const f32x4 kzero = {0.f, 0.f, 0.f, 0.f};

    // prologue: stage phase 0 into buffer 0 (wave w stages tile w)
    {
        const char* src = gB + (size_t)wave * TILEB + (size_t)lane * 16;
        char*       dst = ldsb + wave * TILEB;
        GLOAD_LDS(src, dst);
        GLOAD_LDS(src + 1024, dst + 1024);
    }
    asm volatile("s_waitcnt vmcnt(0)" ::: "memory");
    __syncthreads();

    for (int p = 0; p < nph; ++p) {
        const int cur = p & 1;
        // issue next phase's staging first (hides under this phase's compute)
        if (p + 1 < nph) {
            const char* src = gB + (size_t)(p + 1) * PHB
                            + (size_t)wave * TILEB + (size_t)lane * 16;
            char*       dst = ldsb + (cur ^ 1) * PHB + wave * TILEB;
            GLOAD_LDS(src, dst);
            GLOAD_LDS(src + 1024, dst + 1024);
        }
        const char* bb = ldsb + cur * PHB + lane * 16;
        #pragma unroll
        for (int t = 0; t < PHT; ++t) {
            bf16x8 b0 = *(const bf16x8*)(bb + t * TILEB);
            bf16x8 b1 = *(const bf16x8*)(bb + t * TILEB + 1024);
            #pragma unroll
            for (int s = 0; s < NSETS; ++s) {
                f32x4 acc = __builtin_amdgcn_mfma_f32_16x16x32_bf16(a0[s], b0, kzero, 0, 0, 0);
                acc = __builtin_amdgcn_mfma_f32_16x16x32_bf16(a1[s], b1, acc, 0, 0, 0);
                sum[s * 4 + 0] += EXP2F(acc[0]);
                sum[s * 4 + 1] += EXP2F(acc[1]);
                sum[s * 4 + 2] += EXP2F(acc[2]);
                sum[s * 4 + 3] += EXP2F(acc[3]);
            }
        }
        // staged buffer must be complete & all waves done reading cur
        asm volatile("s_waitcnt vmcnt(0)" ::: "memory");
        __syncthreads();
    }

    // reduce each row-sum across the 16 lanes of the quad, then atomics
    #pragma unroll
    for (int k = 0; k < NSETS * 4; ++k) {
        float v = sum[k];
        #pragma unroll
        for (int o = 1; o < 16; o <<= 1) v += __shfl_xor(v, o);
        sum[k] = v;
    }
    if (l15 == 0) {
        #pragma unroll
        for (int s = 0; s < NSETS; ++s)
            #pragma unroll
            for (int i = 0; i < 4; ++i)
                atomicAdd(&rowsum[wr + s * 16 + q * 4 + i], sum[s * 4 + i]);
    }
}

// ---------------------------------------------------------------- finalize
// 64 blocks x 256 threads: thread t handles one row.
__global__ __launch_bounds__(256) void finalize_kernel(
    const float* __restrict__ rowsum, const float* __restrict__ posv,
    float* __restrict__ out, int N)
{
    int row = blockIdx.x * 256 + threadIdx.x;
    float acc = (LOG2F(rowsum[row]) - posv[row]) * (0.69314718055994531f / (float)N);
    #pragma unroll
    for (int o = 32; o; o >>= 1) acc += __shfl_xor(acc, o);
    if ((threadIdx.x & 63) == 0) atomicAdd(out, acc);
}

// ---------------------------------------------------------------- launch
extern "C" void kernel_launch(void* const* d_in, const int* in_sizes, int n_in,
                              void* d_out, int out_size, void* d_ws, size_t ws_size,
                              hipStream_t stream)
{
    const float* z1 = (const float*)d_in[0];
    const float* z2 = (const float*)d_in[1];
    const int N = in_sizes[0] / DDIM;   // 16384

    char* ws = (char*)d_ws;
    __hip_bfloat16* z1f = (__hip_bfloat16*)ws;                  // N*128 B (2 MB)
    __hip_bfloat16* z2f = z1f + (size_t)N * DDIM;               // N*128 B (2 MB)
    float* rowsum = (float*)(ws + 2 * (size_t)N * DDIM * 2);    // N*4 B
    float* posv   = rowsum + N;                                 // N*4 B

    const float kScale = 28.853900817779268f;   // log2(e) / 0.05

    norm_frag_kernel<<<N / 16, 256, 0, stream>>>(z1, z2, z1f, z2f, rowsum,
                                                 posv, (float*)d_out, kScale, N);

    dim3 grid(N / BM, CS);
    infonce_main_kernel<<<grid, NW * 64, 0, stream>>>(z1f, z2f, rowsum, N);

    finalize_kernel<<<N / 256, 256, 0, stream>>>(rowsum, posv, (float*)d_out, N);
}

// Round 4
// 104.663 us; speedup vs baseline: 1.0539x; 1.0333x over previous
//
#include <hip/hip_runtime.h>
#include <hip/hip_bf16.h>

// InfoNCE fused: loss = (1/N) sum_i [ log(sum_j exp(sim_ij)) - sim_ii ]
// sim = (z1/||z1||)@(z2/||z2||)^T / tau.  logits=[pos, diag-masked row] with
// pos == sim_ii => lse over the FULL row (diagonal included).
//
// z1f = bf16(z1n * log2(e)/tau) so exp(sim) = exp2(MFMA output); values in
// [-29,29] in log2 domain -> raw v_exp_f32 (__builtin_amdgcn_exp2f), NOT libm.
//
// R11 vs R10 (49.2 us main): phased-LDS fixed B traffic but occupancy fell
// to 31% and every 4-tile phase paid a vmcnt(0)+barrier drain with only
// 2.5 blocks/CU resident -> ~50% dead slack on both pipes (MfmaUtil 27,
// VALUBusy 46; floor is ~18us). Fix: stage the ENTIRE per-block B panel
// (CS=64 -> colspan=256 -> 32KB) into LDS up front; ONE barrier total,
// then 16 barrier-free compute iterations. 32KB -> 5 blocks/CU = 5
// waves/SIMD under __launch_bounds__(256,5) (~102-reg budget, need ~76).
// Predict: main ~22-27us, VALUBusy ~70%, MfmaUtil ~55%, occ ~60%.

typedef __bf16  bf16x8 __attribute__((ext_vector_type(8)));
typedef __bf16  bf16x4 __attribute__((ext_vector_type(4)));
typedef float   f32x4  __attribute__((ext_vector_type(4)));

#if __has_builtin(__builtin_amdgcn_exp2f)
#define EXP2F(x) __builtin_amdgcn_exp2f(x)   // raw v_exp_f32
#else
#define EXP2F(x) exp2f(x)
#endif
#if __has_builtin(__builtin_amdgcn_logf)
#define LOG2F(x) __builtin_amdgcn_logf(x)    // raw v_log_f32
#else
#define LOG2F(x) log2f(x)
#endif

#define DDIM   64
#define TILEB  2048         // bytes per fragment-ordered 16-col tile
#define NSETS  4            // 16-row MFMA sets per wave (64 rows/wave)
#define NW     4            // waves per block
#define BM     (NW * NSETS * 16)   // 256 rows per block
#define CS     64           // column splits -> grid (64,64) = 4096 blocks
#define LDSB   32768        // colspan(256) * 128 B  (assumes N == 16384)

// global -> LDS async copy, 16 B per lane; LDS dest is wave-uniform base
// (+ lane*16 implicit in HW), global src is per-lane (linear both sides).
#define GLOAD_LDS(g, l)                                                      \
    __builtin_amdgcn_global_load_lds(                                        \
        (const __attribute__((address_space(1))) void*)(g),                  \
        (__attribute__((address_space(3))) void*)(l), 16, 0, 0)

// ---------------------------------------------------------------- normalize
// One block per 16-row tile. Thread (r = tid>>4, c = tid&15) loads
// z[row, 4c..4c+4), reduces ||row|| over its 16-lane group, writes the 4
// bf16 values into fragment order:
//   byte off(tile) = (c>>3)*1024 + ((c>>1)&3)*256 + r*16 + (c&1)*8
// Same thread holds row i of both views -> posv[i] = dot(z1f_i, z2f_i)
// computed here (bf16-rounded, matches MFMA diagonal). Zeroes rowsum; block 0
// zeroes d_out (stream-ordered before finalize's atomics).
__global__ __launch_bounds__(256) void norm_frag_kernel(
    const float* __restrict__ z1, const float* __restrict__ z2,
    __hip_bfloat16* __restrict__ z1f, __hip_bfloat16* __restrict__ z2f,
    float* __restrict__ rowsum, float* __restrict__ posv,
    float* __restrict__ out, float scale1, int N)
{
    const int tid  = threadIdx.x;
    const int r    = tid >> 4, c = tid & 15;
    const int tile = blockIdx.x;
    const size_t row = (size_t)tile * 16 + r;
    const size_t off = (size_t)tile * TILEB
                     + ((c >> 3) << 10) + (((c >> 1) & 3) << 8)
                     + (r << 4) + ((c & 1) << 3);

    bf16x4 o1, o2;
    // z1 (scaled by log2(e)/tau)
    {
        float4 v = *(const float4*)(z1 + row * DDIM + c * 4);
        float ss = v.x*v.x + v.y*v.y + v.z*v.z + v.w*v.w;
        #pragma unroll
        for (int o = 8; o; o >>= 1) ss += __shfl_xor(ss, o);
        float inv = scale1 / fmaxf(sqrtf(ss), 1e-12f);
        o1 = (bf16x4){ __float2bfloat16(v.x*inv), __float2bfloat16(v.y*inv),
                       __float2bfloat16(v.z*inv), __float2bfloat16(v.w*inv) };
        *(bf16x4*)((char*)z1f + off) = o1;
    }
    // z2 (unit scale)
    {
        float4 v = *(const float4*)(z2 + row * DDIM + c * 4);
        float ss = v.x*v.x + v.y*v.y + v.z*v.z + v.w*v.w;
        #pragma unroll
        for (int o = 8; o; o >>= 1) ss += __shfl_xor(ss, o);
        float inv = 1.0f / fmaxf(sqrtf(ss), 1e-12f);
        o2 = (bf16x4){ __float2bfloat16(v.x*inv), __float2bfloat16(v.y*inv),
                       __float2bfloat16(v.z*inv), __float2bfloat16(v.w*inv) };
        *(bf16x4*)((char*)z2f + off) = o2;
    }

    // posv[row] = dot of the bf16-rounded rows (log2-domain positive logit)
    float p = (float)o1[0]*(float)o2[0] + (float)o1[1]*(float)o2[1]
            + (float)o1[2]*(float)o2[2] + (float)o1[3]*(float)o2[3];
    #pragma unroll
    for (int o = 8; o; o >>= 1) p += __shfl_xor(p, o);
    if (c == 0) posv[row] = p;

    if (tid < 16) rowsum[(size_t)tile * 16 + tid] = 0.f;
    if (tile == 0 && tid == 0) *out = 0.f;
}

// ---------------------------------------------------------------- main
// Per block: 256 rows (4 waves x 4 sets) x colspan=256 cols. The block's
// ENTIRE 32KB B panel is staged into LDS up front (each wave 8x 1KB
// global_load_lds chunks, interleaved), one vmcnt(0)+barrier, then 16
// barrier-free iterations: 2x ds_read_b128, 8 MFMA, 16 exp2, 16 add.
__global__ __launch_bounds__(256, 5) void infonce_main_kernel(
    const __hip_bfloat16* __restrict__ z1f,
    const __hip_bfloat16* __restrict__ z2f,
    float* __restrict__ rowsum,    // fp32, atomic partial rowsums of 2^C
    int N)
{
    __shared__ __align__(16) char ldsb[LDSB];   // 32 KB -> 5 blocks/CU

    const int tid  = threadIdx.x;
    const int wave = tid >> 6;
    const int lane = tid & 63;
    const int q    = lane >> 4;
    const int l15  = lane & 15;

    const int colspan = N / CS;          // 256
    const int ntiles  = colspan >> 4;    // 16
    const int c0      = blockIdx.y * colspan;
    const int wr      = blockIdx.x * BM + wave * (NSETS * 16);

    const char* gB = (const char*)z2f + (size_t)(c0 >> 4) * TILEB;

    // stage the whole B panel: 32 chunks of 1KB, wave-interleaved
    {
        const int nchunks = (ntiles * TILEB) >> 10;   // 32
        for (int i = 0; i < nchunks / NW; ++i) {
            const int c = i * NW + wave;
            GLOAD_LDS(gB + (c << 10) + lane * 16, ldsb + (c << 10));
        }
    }

    // A fragments for NSETS row-tiles (coalesced: fragment-ordered global)
    bf16x8 a0[NSETS], a1[NSETS];
    #pragma unroll
    for (int s = 0; s < NSETS; ++s) {
        const char* ab = (const char*)z1f + (size_t)((wr >> 4) + s) * TILEB + lane * 16;
        a0[s] = *(const bf16x8*)(ab);
        a1[s] = *(const bf16x8*)(ab + 1024);
    }

    float sum[NSETS * 4];
    #pragma unroll
    for (int k = 0; k < NSETS * 4; ++k) sum[k] = 0.f;

    asm volatile("s_waitcnt vmcnt(0)" ::: "memory");
    __syncthreads();                      // the ONLY barrier

    const char* bb = ldsb + lane * 16;
    const f32x4 kzero = {0.f, 0.f, 0.f, 0.f};

    #pragma unroll 4
    for (int t = 0; t < ntiles; ++t) {
        bf16x8 b0 = *(const bf16x8*)(bb + t * TILEB);
        bf16x8 b1 = *(const bf16x8*)(bb + t * TILEB + 1024);
        #pragma unroll
        for (int s = 0; s < NSETS; ++s) {
            f32x4 acc = __builtin_amdgcn_mfma_f32_16x16x32_bf16(a0[s], b0, kzero, 0, 0, 0);
            acc = __builtin_amdgcn_mfma_f32_16x16x32_bf16(a1[s], b1, acc, 0, 0, 0);
            sum[s * 4 + 0] += EXP2F(acc[0]);
            sum[s * 4 + 1] += EXP2F(acc[1]);
            sum[s * 4 + 2] += EXP2F(acc[2]);
            sum[s * 4 + 3] += EXP2F(acc[3]);
        }
    }

    // reduce each row-sum across the 16 lanes of the quad, then atomics
    #pragma unroll
    for (int k = 0; k < NSETS * 4; ++k) {
        float v = sum[k];
        #pragma unroll
        for (int o = 1; o < 16; o <<= 1) v += __shfl_xor(v, o);
        sum[k] = v;
    }
    if (l15 == 0) {
        #pragma unroll
        for (int s = 0; s < NSETS; ++s)
            #pragma unroll
            for (int i = 0; i < 4; ++i)
                atomicAdd(&rowsum[wr + s * 16 + q * 4 + i], sum[s * 4 + i]);
    }
}

// ---------------------------------------------------------------- finalize
// 64 blocks x 256 threads: thread t handles one row.
__global__ __launch_bounds__(256) void finalize_kernel(
    const float* __restrict__ rowsum, const float* __restrict__ posv,
    float* __restrict__ out, int N)
{
    int row = blockIdx.x * 256 + threadIdx.x;
    float acc = (LOG2F(rowsum[row]) - posv[row]) * (0.69314718055994531f / (float)N);
    #pragma unroll
    for (int o = 32; o; o >>= 1) acc += __shfl_xor(acc, o);
    if ((threadIdx.x & 63) == 0) atomicAdd(out, acc);
}

// ---------------------------------------------------------------- launch
extern "C" void kernel_launch(void* const* d_in, const int* in_sizes, int n_in,
                              void* d_out, int out_size, void* d_ws, size_t ws_size,
                              hipStream_t stream)
{
    const float* z1 = (const float*)d_in[0];
    const float* z2 = (const float*)d_in[1];
    const int N = in_sizes[0] / DDIM;   // 16384

    char* ws = (char*)d_ws;
    __hip_bfloat16* z1f = (__hip_bfloat16*)ws;                  // N*128 B (2 MB)
    __hip_bfloat16* z2f = z1f + (size_t)N * DDIM;               // N*128 B (2 MB)
    float* rowsum = (float*)(ws + 2 * (size_t)N * DDIM * 2);    // N*4 B
    float* posv   = rowsum + N;                                 // N*4 B

    const float kScale = 28.853900817779268f;   // log2(e) / 0.05

    norm_frag_kernel<<<N / 16, 256, 0, stream>>>(z1, z2, z1f, z2f, rowsum,
                                                 posv, (float*)d_out, kScale, N);

    dim3 grid(N / BM, CS);
    infonce_main_kernel<<<grid, NW * 64, 0, stream>>>(z1f, z2f, rowsum, N);

    finalize_kernel<<<N / 256, 256, 0, stream>>>(rowsum, posv, (float*)d_out, N);
}